// Round 10
// baseline (915.551 us; speedup 1.0000x reference)
//
#include <hip/hip_runtime.h>
#include <hip/hip_bf16.h>

// Problem constants
#define NB    1024   // batch
#define SEQ   512    // max seq len
#define DIM   128    // embedding dim (D)
#define HID   128    // hidden (H)
#define NOPS  16     // OPS
#define FEAT  144    // H + OPS
#define BQ    2      // samples per WG -> grid 512 -> TWO independent WGs/CU
#define AST   144    // sample stride inside a slot (bf16): breaks pow-2 bank strides
#define XST   290    // x slot stride (bf16) = 145 dwords (odd mod 32)
#define HST   (BQ * AST)   // h parity-slab stride

typedef __bf16 bf16x8 __attribute__((ext_vector_type(8)));
typedef float  floatx4 __attribute__((ext_vector_type(4)));

__device__ __forceinline__ float fsig(float x)  { return 1.0f / (1.0f + __expf(-x)); }
__device__ __forceinline__ float ftanhf(float x){ return 2.0f / (1.0f + __expf(-2.0f * x)) - 1.0f; }

// LDS-only barrier: drains lgkmcnt, leaves global gathers in flight.
__device__ __forceinline__ void block_sync_lds() {
    asm volatile("s_waitcnt lgkmcnt(0)\n\ts_barrier" ::: "memory");
}

// R6 structure (champion, 527us) at BQ=2 with grid 512: two INDEPENDENT
// 8-wave WGs co-reside per CU (R6 wave = 108 VGPRs -> 4 waves/SIMD fit;
// launch_bounds(512,2) caps at 256 so the compiler does not clamp to the
// 64-reg granule like R8/R9 did -> no spill). Uncoupled barriers: one WG's
// dep-chain/barrier stalls are filled by the other's issue. Wave w owns
// unit-chunk w for all 4 gates; 4-step x-packing (A row = s*8+d*4+off, d =
// benign duplicate); in-loop serial MFMAs are h-part only with C = xg fed
// directly; 8 rotating x-slots (odd-dword stride); one LDS barrier/step;
// staging on waves 0-3 (tid<256), wave-uniform.
__global__ __launch_bounds__(512, 2)
void lstm_fused(const int* __restrict__ tokens, const int* __restrict__ lengths,
                const float* __restrict__ onehot, const float* __restrict__ emb,
                const float* __restrict__ Wih, const float* __restrict__ Whh,
                const float* __restrict__ bih, const float* __restrict__ bhh,
                const float* __restrict__ h0, const float* __restrict__ c0,
                const float* __restrict__ linW, const float* __restrict__ linb,
                float* __restrict__ out)
{
    __shared__ __align__(16) __bf16 xbuf[8 * XST];   // 8 rotating x slots
    __shared__ __align__(16) __bf16 hbuf[2 * HST];   // h, parity by t&1
    __shared__ __align__(16) float  hlbuf[BQ * HID];

    const int tid  = threadIdx.x;
    const int wave = tid >> 6;
    const int lane = tid & 63;
    const int quad = lane >> 4;
    const int lrow = lane & 15;
    const int bid  = blockIdx.x;

    // ---- Weight B-fragments in registers (loaded once). ----
    // B-layout (16x16x32): lane holds B[k=quad*8+j][n=lrow].
    bf16x8 wfx[4][4], wfh[4][4];
#pragma unroll
    for (int gt = 0; gt < 4; ++gt) {
        const int g = gt * 128 + wave * 16 + lrow;
#pragma unroll
        for (int kt = 0; kt < 4; ++kt) {
            const float* sx = Wih + g * DIM + kt * 32 + quad * 8;
            const float* sh = Whh + g * HID + kt * 32 + quad * 8;
            float4 a = *(const float4*)(sx);
            float4 b = *(const float4*)(sx + 4);
            bf16x8 v;
            v[0] = (__bf16)a.x; v[1] = (__bf16)a.y; v[2] = (__bf16)a.z; v[3] = (__bf16)a.w;
            v[4] = (__bf16)b.x; v[5] = (__bf16)b.y; v[6] = (__bf16)b.z; v[7] = (__bf16)b.w;
            wfx[gt][kt] = v;
            a = *(const float4*)(sh);
            b = *(const float4*)(sh + 4);
            v[0] = (__bf16)a.x; v[1] = (__bf16)a.y; v[2] = (__bf16)a.z; v[3] = (__bf16)a.w;
            v[4] = (__bf16)b.x; v[5] = (__bf16)b.y; v[6] = (__bf16)b.z; v[7] = (__bf16)b.w;
            wfh[gt][kt] = v;
        }
    }

    // ---- Per-lane state: sample = quad>>1, unit = uu = wave*16 + lrow ----
    const int uu = wave * 16 + lrow;
    const int sq = quad >> 1;
    const int bq = bid * BQ + sq;
    int lenq = lengths[bq]; if (lenq < 1) lenq = 1;
    const int tlast = lenq - 1;

    int Lmax = 0;
#pragma unroll
    for (int s2 = 0; s2 < BQ; ++s2) {
        int l2 = lengths[bid * BQ + s2]; if (l2 < 1) l2 = 1;
        Lmax = (l2 > Lmax) ? l2 : Lmax;
    }

    // persistent bias C-registers: xg chains start from these (no splats)
    floatx4 biasC[4];
#pragma unroll
    for (int gt = 0; gt < 4; ++gt) {
        const float bgt = bih[gt * 128 + uu] + bhh[gt * 128 + uu];
        floatx4 a0 = {bgt, bgt, bgt, bgt};
        biasC[gt] = a0;
    }

    float c  = c0[uu];
    float hl = 0.0f;

    // ---- Staging thread layout (waves 0-3 only): m over 2 samples ----
    const int m  = (tid >> 7) & 1;
    const int u  = tid & 127;
    const int bm = bid * BQ + m;
    const int sm = m * AST + u;
    const bool stager = (tid < 256);   // wave-uniform

    float e = 0.0f;
    if (stager) {
        hbuf[sm] = (__bf16)h0[u];
#pragma unroll
        for (int k = 0; k <= 4; ++k) {   // stage x(0..4) into slots 0..4
            float ek = emb[(unsigned)(tokens[bm * SEQ + k] * DIM) + u];
            xbuf[k * XST + sm] = (__bf16)fmaxf(ek, 0.0f);
        }
        e = emb[(unsigned)(tokens[bm * SEQ + 5] * DIM) + u];   // row for x(5)
    }

    // frag pointers: x A-row = lrow -> (sample = lrow>>3, off = lrow&3)
    const int xfbase = (lrow & 3) * XST + (lrow >> 3) * AST + quad * 8;
    const __bf16* const xfp[2] = { &xbuf[xfbase], &xbuf[4 * XST + xfbase] };
    const int habase = (lrow >> 3) * AST + quad * 8;
    const __bf16* const hf[2] = { &hbuf[habase], &hbuf[HST + habase] };
    __bf16* const hw[2] = { &hbuf[sq * AST + uu], &hbuf[HST + sq * AST + uu] };
    __bf16* const xw = &xbuf[sm];

    __syncthreads();   // x(0..4), h(0) staged

    // xg[gt][r] = bias + x(ts+r)@W_ih^T for (sample sq, unit uu)
    floatx4 xg[4];
#define XBLOCK(G) do {                                                               \
        bf16x8 af_[4];                                                               \
        _Pragma("unroll") for (int kt = 0; kt < 4; ++kt)                             \
            af_[kt] = *(const bf16x8*)(xfp[G] + kt * 32);                            \
        _Pragma("unroll") for (int gt = 0; gt < 4; ++gt)                             \
            xg[gt] = __builtin_amdgcn_mfma_f32_16x16x32_bf16(af_[0], wfx[gt][0], biasC[gt], 0, 0, 0); \
        _Pragma("unroll") for (int kt = 1; kt < 4; ++kt)                             \
            _Pragma("unroll") for (int gt = 0; gt < 4; ++gt)                         \
                xg[gt] = __builtin_amdgcn_mfma_f32_16x16x32_bf16(af_[kt], wfx[gt][kt], xg[gt], 0, 0, 0); \
    } while (0)

    XBLOCK(0);   // xg for superstep 0 (t = 0..3)

    // OFF literal 0..3: parity/slot/extract-index compile-time. h-chain takes
    // C = xg[gt] directly; C/D row quad*4+OFF = (sample sq, t = ts+OFF).
#define STEP(OFF) do {                                                               \
        const int t  = ts + OFF;                                                     \
        bf16x8 ah_[4];                                                               \
        _Pragma("unroll") for (int kt = 0; kt < 4; ++kt)                             \
            ah_[kt] = *(const bf16x8*)(hf[OFF & 1] + kt * 32);                       \
        floatx4 acc[4];                                                              \
        _Pragma("unroll") for (int gt = 0; gt < 4; ++gt)                             \
            acc[gt] = __builtin_amdgcn_mfma_f32_16x16x32_bf16(ah_[0], wfh[gt][0], xg[gt], 0, 0, 0); \
        _Pragma("unroll") for (int kt = 1; kt < 4; ++kt)                             \
            _Pragma("unroll") for (int gt = 0; gt < 4; ++gt)                         \
                acc[gt] = __builtin_amdgcn_mfma_f32_16x16x32_bf16(ah_[kt], wfh[gt][kt], acc[gt], 0, 0, 0); \
        const float ii = fsig(acc[0][OFF]);                                          \
        const float ff = fsig(acc[1][OFF]);                                          \
        const float g2 = ftanhf(acc[2][OFF]);                                        \
        const float oo = fsig(acc[3][OFF]);                                          \
        c = ff * c + ii * g2;                                                        \
        const float h = oo * ftanhf(c);                                              \
        if (t == tlast) hl = fmaxf(h, 0.0f);                                         \
        *hw[1 - (OFF & 1)] = (__bf16)h;   /* duplicate quads write same value */     \
        if (stager && t + 5 < SEQ) {   /* stage x(t+5); slot rotation */             \
            const int slot = (OFF == 3) ? (4 * g) : (4 * (1 - g) + OFF + 1);         \
            xw[slot * XST] = (__bf16)fmaxf(e, 0.0f);                                 \
            if (t + 6 < SEQ)                                                         \
                e = emb[(unsigned)(tokens[bm * SEQ + t + 6] * DIM) + u];             \
        }                                                                            \
        if (OFF == 3 && ts + 4 < Lmax) { XBLOCK(1 - g); }                            \
        block_sync_lds();                                                            \
    } while (0)

    for (int ts = 0; ts < Lmax; ts += 4) {
        const int g = (ts >> 2) & 1;
        STEP(0); STEP(1); STEP(2); STEP(3);
    }
#undef STEP
#undef XBLOCK

    // ---- epilogue: out[b] = [relu(h_last) | onehot] @ linW^T + linb ----
    hlbuf[sq * HID + uu] = hl;   // duplicate quads write same value
    __syncthreads();
    if (tid < 2 * BQ) {
        const int mm = tid >> 1, kk = tid & 1;
        const int bb = bid * BQ + mm;
        float a2 = linb[kk];
        for (int q = 0; q < HID; ++q)
            a2 += hlbuf[mm * HID + q] * linW[kk * FEAT + q];
        for (int o = 0; o < NOPS; ++o)
            a2 += onehot[bb * NOPS + o] * linW[kk * FEAT + HID + o];
        out[bb * 2 + kk] = a2;
    }
}

extern "C" void kernel_launch(void* const* d_in, const int* in_sizes, int n_in,
                              void* d_out, int out_size, void* d_ws, size_t ws_size,
                              hipStream_t stream) {
    const int*   tokens  = (const int*)d_in[0];
    const int*   lengths = (const int*)d_in[1];
    const float* onehot  = (const float*)d_in[2];
    const float* emb     = (const float*)d_in[3];
    const float* Wih     = (const float*)d_in[4];
    const float* Whh     = (const float*)d_in[5];
    const float* bih     = (const float*)d_in[6];
    const float* bhh     = (const float*)d_in[7];
    const float* h0      = (const float*)d_in[8];
    const float* c0      = (const float*)d_in[9];
    const float* linW    = (const float*)d_in[10];
    const float* linb    = (const float*)d_in[11];
    float* out = (float*)d_out;
    (void)in_sizes; (void)n_in; (void)out_size; (void)d_ws; (void)ws_size;

    lstm_fused<<<dim3(NB / BQ), dim3(512), 0, stream>>>(
        tokens, lengths, onehot, emb, Wih, Whh, bih, bhh, h0, c0, linW, linb, out);
}

// Round 11
// 576.250 us; speedup vs baseline: 1.5888x; 1.5888x over previous
//
#include <hip/hip_runtime.h>
#include <hip/hip_bf16.h>

// Problem constants
#define NB    1024   // batch
#define SEQ   512    // max seq len
#define DIM   128    // embedding dim (D)
#define HID   128    // hidden (H)
#define NOPS  16     // OPS
#define FEAT  144    // H + OPS
#define BQ    4      // samples per workgroup
#define AST   144    // sample stride inside a slot (bf16): breaks pow-2 bank strides
#define XST   578    // x slot stride (bf16) = 289 dwords, odd mod 32 -> ~2-way frag reads

typedef __bf16 bf16x8 __attribute__((ext_vector_type(8)));
typedef float  floatx4 __attribute__((ext_vector_type(4)));

__device__ __forceinline__ float fsig(float x)  { return 1.0f / (1.0f + __expf(-x)); }
__device__ __forceinline__ float ftanhf(float x){ return 2.0f / (1.0f + __expf(-2.0f * x)) - 1.0f; }

// LDS-only barrier: drains lgkmcnt (all cross-wave traffic is LDS), leaves
// global gathers in flight.
__device__ __forceinline__ void block_sync_lds() {
    asm volatile("s_waitcnt lgkmcnt(0)\n\ts_barrier" ::: "memory");
}

// CHAMPION STRUCTURE (R6, 527us) restored after R7-R10 exploration all
// regressed. One WG = 512 threads (8 waves) owns BQ=4 samples, 1 WG/CU.
// Register reality (proven R8/R9/R10): weight frags = 128 regs/wave (AGPR),
// working set ~108 VGPR -> ~236 total/wave -> 2 waves/SIMD is the hard cap;
// every attempt at 4 waves/SIMD spills or fails to co-reside. Wave w owns
// unit-chunk w for all 4 gate types (gates consumed in-register). 4-step
// x-packing: one MFMA block per superstep computes x-gates for 4 samples x
// 4 timesteps (A row = sample*4 + off); xg[gt][r] lands per-lane. In-loop
// serial MFMAs are h-part only (16/wave/step), C = xg fed directly (no acc
// copies / bias splats / extract selects). 8 rotating x-slots, stride 578
// (odd dwords -> ~2-way bank access). One LDS barrier per step. Only delta
// vs R6: 32-bit embedding indexing (token*128+u < 2^23).
__global__ __launch_bounds__(512, 2)
void lstm_fused(const int* __restrict__ tokens, const int* __restrict__ lengths,
                const float* __restrict__ onehot, const float* __restrict__ emb,
                const float* __restrict__ Wih, const float* __restrict__ Whh,
                const float* __restrict__ bih, const float* __restrict__ bhh,
                const float* __restrict__ h0, const float* __restrict__ c0,
                const float* __restrict__ linW, const float* __restrict__ linb,
                float* __restrict__ out)
{
    __shared__ __align__(16) __bf16 xbuf[8 * XST];        // 8 rotating x slots
    __shared__ __align__(16) __bf16 hbuf[2 * BQ * AST];   // h, parity by t&1
    __shared__ __align__(16) float  hlbuf[BQ * HID];

    const int tid  = threadIdx.x;
    const int wave = tid >> 6;
    const int lane = tid & 63;
    const int quad = lane >> 4;
    const int lrow = lane & 15;
    const int bid  = blockIdx.x;

    // ---- Weight B-fragments in registers (loaded once). ----
    // B-layout (16x16x32): lane holds B[k=quad*8+j][n=lrow].
    bf16x8 wfx[4][4], wfh[4][4];
#pragma unroll
    for (int gt = 0; gt < 4; ++gt) {
        const int g = gt * 128 + wave * 16 + lrow;
#pragma unroll
        for (int kt = 0; kt < 4; ++kt) {
            const float* sx = Wih + g * DIM + kt * 32 + quad * 8;
            const float* sh = Whh + g * HID + kt * 32 + quad * 8;
            float4 a = *(const float4*)(sx);
            float4 b = *(const float4*)(sx + 4);
            bf16x8 v;
            v[0] = (__bf16)a.x; v[1] = (__bf16)a.y; v[2] = (__bf16)a.z; v[3] = (__bf16)a.w;
            v[4] = (__bf16)b.x; v[5] = (__bf16)b.y; v[6] = (__bf16)b.z; v[7] = (__bf16)b.w;
            wfx[gt][kt] = v;
            a = *(const float4*)(sh);
            b = *(const float4*)(sh + 4);
            v[0] = (__bf16)a.x; v[1] = (__bf16)a.y; v[2] = (__bf16)a.z; v[3] = (__bf16)a.w;
            v[4] = (__bf16)b.x; v[5] = (__bf16)b.y; v[6] = (__bf16)b.z; v[7] = (__bf16)b.w;
            wfh[gt][kt] = v;
        }
    }

    // ---- Per-lane state: sample = quad, unit = uu = wave*16 + lrow ----
    const int uu = wave * 16 + lrow;
    const int bq = bid * BQ + quad;
    int lenq = lengths[bq]; if (lenq < 1) lenq = 1;
    const int tlast = lenq - 1;

    int Lmax = 0;
#pragma unroll
    for (int s2 = 0; s2 < BQ; ++s2) {
        int l2 = lengths[bid * BQ + s2]; if (l2 < 1) l2 = 1;
        Lmax = (l2 > Lmax) ? l2 : Lmax;
    }

    // persistent bias C-registers: xg chains start from these (no splats)
    floatx4 biasC[4];
#pragma unroll
    for (int gt = 0; gt < 4; ++gt) {
        const float bgt = bih[gt * 128 + uu] + bhh[gt * 128 + uu];
        floatx4 a0 = {bgt, bgt, bgt, bgt};
        biasC[gt] = a0;
    }

    float c  = c0[uu];
    float hl = 0.0f;

    // ---- Staging thread layout: m = tid>>7 (sample), u = tid&127 (unit) ----
    const int m  = tid >> 7;
    const int u  = tid & 127;
    const int bm = bid * BQ + m;
    const int sm = m * AST + u;

    hbuf[sm] = (__bf16)h0[u];
#pragma unroll
    for (int k = 0; k <= 4; ++k) {   // stage x(0..4) into slots 0..4
        float ek = emb[(unsigned)(tokens[bm * SEQ + k] * DIM) + u];
        xbuf[k * XST + sm] = (__bf16)fmaxf(ek, 0.0f);
    }
    float e = emb[(unsigned)(tokens[bm * SEQ + 5] * DIM) + u];   // row for x(5)

    // frag pointers: x A-row = lrow -> (sample = lrow>>2, off = lrow&3)
    const int xfbase = (lrow & 3) * XST + (lrow >> 2) * AST + quad * 8;
    const __bf16* const xfp[2] = { &xbuf[xfbase], &xbuf[4 * XST + xfbase] };
    const int habase = (lrow >> 2) * AST + quad * 8;
    const __bf16* const hf[2] = { &hbuf[habase], &hbuf[BQ * AST + habase] };
    __bf16* const hw[2] = { &hbuf[quad * AST + uu], &hbuf[BQ * AST + quad * AST + uu] };
    __bf16* const xw = &xbuf[sm];

    __syncthreads();   // x(0..4), h(0) staged

    // xg[gt][r] = bias + x(ts+r)@W_ih^T for (sample quad, unit uu)
    floatx4 xg[4];
#define XBLOCK(G) do {                                                               \
        bf16x8 af_[4];                                                               \
        _Pragma("unroll") for (int kt = 0; kt < 4; ++kt)                             \
            af_[kt] = *(const bf16x8*)(xfp[G] + kt * 32);                            \
        _Pragma("unroll") for (int gt = 0; gt < 4; ++gt)                             \
            xg[gt] = __builtin_amdgcn_mfma_f32_16x16x32_bf16(af_[0], wfx[gt][0], biasC[gt], 0, 0, 0); \
        _Pragma("unroll") for (int kt = 1; kt < 4; ++kt)                             \
            _Pragma("unroll") for (int gt = 0; gt < 4; ++gt)                         \
                xg[gt] = __builtin_amdgcn_mfma_f32_16x16x32_bf16(af_[kt], wfx[gt][kt], xg[gt], 0, 0, 0); \
    } while (0)

    XBLOCK(0);   // xg for superstep 0 (t = 0..3)

    // OFF is a literal 0..3: parity/slot/extract-index all compile-time.
    // h-chain takes C = xg[gt] directly; C/D row quad*4+OFF = (sample quad,
    // t = ts+OFF) -> elem OFF of acc is this lane's gate preact.
#define STEP(OFF) do {                                                               \
        const int t  = ts + OFF;                                                     \
        bf16x8 ah_[4];                                                               \
        _Pragma("unroll") for (int kt = 0; kt < 4; ++kt)                             \
            ah_[kt] = *(const bf16x8*)(hf[OFF & 1] + kt * 32);                       \
        floatx4 acc[4];                                                              \
        _Pragma("unroll") for (int gt = 0; gt < 4; ++gt)                             \
            acc[gt] = __builtin_amdgcn_mfma_f32_16x16x32_bf16(ah_[0], wfh[gt][0], xg[gt], 0, 0, 0); \
        _Pragma("unroll") for (int kt = 1; kt < 4; ++kt)                             \
            _Pragma("unroll") for (int gt = 0; gt < 4; ++gt)                         \
                acc[gt] = __builtin_amdgcn_mfma_f32_16x16x32_bf16(ah_[kt], wfh[gt][kt], acc[gt], 0, 0, 0); \
        const float ii = fsig(acc[0][OFF]);                                          \
        const float ff = fsig(acc[1][OFF]);                                          \
        const float g2 = ftanhf(acc[2][OFF]);                                        \
        const float oo = fsig(acc[3][OFF]);                                          \
        c = ff * c + ii * g2;                                                        \
        const float h = oo * ftanhf(c);                                              \
        if (t == tlast) hl = fmaxf(h, 0.0f);                                         \
        *hw[1 - (OFF & 1)] = (__bf16)h;                                              \
        if (t + 5 < SEQ) {   /* stage x(t+5); slot rotation, compile-time OFF */     \
            const int slot = (OFF == 3) ? (4 * g) : (4 * (1 - g) + OFF + 1);         \
            xw[slot * XST] = (__bf16)fmaxf(e, 0.0f);                                 \
            if (t + 6 < SEQ)                                                         \
                e = emb[(unsigned)(tokens[bm * SEQ + t + 6] * DIM) + u];             \
        }                                                                            \
        if (OFF == 3 && ts + 4 < Lmax) { XBLOCK(1 - g); }                            \
        block_sync_lds();                                                            \
    } while (0)

    for (int ts = 0; ts < Lmax; ts += 4) {
        const int g = (ts >> 2) & 1;
        STEP(0); STEP(1); STEP(2); STEP(3);
    }
#undef STEP
#undef XBLOCK

    // ---- epilogue: out[b] = [relu(h_last) | onehot] @ linW^T + linb ----
    hlbuf[quad * HID + uu] = hl;
    __syncthreads();
    if (tid < 2 * BQ) {
        const int mm = tid >> 1, kk = tid & 1;
        const int bb = bid * BQ + mm;
        float a2 = linb[kk];
        for (int q = 0; q < HID; ++q)
            a2 += hlbuf[mm * HID + q] * linW[kk * FEAT + q];
        for (int o = 0; o < NOPS; ++o)
            a2 += onehot[bb * NOPS + o] * linW[kk * FEAT + HID + o];
        out[bb * 2 + kk] = a2;
    }
}

extern "C" void kernel_launch(void* const* d_in, const int* in_sizes, int n_in,
                              void* d_out, int out_size, void* d_ws, size_t ws_size,
                              hipStream_t stream) {
    const int*   tokens  = (const int*)d_in[0];
    const int*   lengths = (const int*)d_in[1];
    const float* onehot  = (const float*)d_in[2];
    const float* emb     = (const float*)d_in[3];
    const float* Wih     = (const float*)d_in[4];
    const float* Whh     = (const float*)d_in[5];
    const float* bih     = (const float*)d_in[6];
    const float* bhh     = (const float*)d_in[7];
    const float* h0      = (const float*)d_in[8];
    const float* c0      = (const float*)d_in[9];
    const float* linW    = (const float*)d_in[10];
    const float* linb    = (const float*)d_in[11];
    float* out = (float*)d_out;
    (void)in_sizes; (void)n_in; (void)out_size; (void)d_ws; (void)ws_size;

    lstm_fused<<<dim3(NB / BQ), dim3(512), 0, stream>>>(
        tokens, lengths, onehot, emb, Wih, Whh, bih, bhh, h0, c0, linW, linb, out);
}